// Round 4
// baseline (385.380 us; speedup 1.0000x reference)
//
#include <hip/hip_runtime.h>
#include <cstdint>
#include <cstddef>

typedef unsigned short u16;
typedef __attribute__((ext_vector_type(8))) short short8v;   // 8 x bf16 (4 VGPRs)
typedef __attribute__((ext_vector_type(4))) float f32x4;

#define B_   2
#define L_   2048
#define D_   1024
#define NH_  16
#define DH_  64
#define M_   (B_*L_)      /* 4096 */
#define N4_  (4*D_)       /* 4096 */

__device__ __forceinline__ float bf2f(u16 u) {
  union { float f; unsigned int i; } v; v.i = ((unsigned int)u) << 16; return v.f;
}
__device__ __forceinline__ u16 f2bf(float f) {
  union { float f; unsigned int i; } v; v.f = f;
  unsigned int x = v.i;
  return (u16)((x + 0x7fffu + ((x >> 16) & 1u)) >> 16);   // RNE
}
__device__ __forceinline__ unsigned int pk_bf16(float a, float b) {
#if __has_builtin(__builtin_amdgcn_cvt_pk_bf16_f32)
  auto r = __builtin_amdgcn_cvt_pk_bf16_f32(a, b);
  union { decltype(r) v; unsigned int u; } c; c.v = r; return c.u;
#else
  unsigned int r;
  asm("v_cvt_pk_bf16_f32 %0, %1, %2" : "=v"(r) : "v"(a), "v"(b));
  return r;
#endif
}
// silu via v_rcp_f32 (approx rcp, ~1ulp) instead of IEEE divide
__device__ __forceinline__ float siluf(float x) {
  return x * __builtin_amdgcn_rcpf(1.0f + __expf(-x));
}

// async global->LDS, 16B per lane. LDS dest = wave-uniform base + lane*16.
__device__ __forceinline__ void gl2lds16(const u16* g, u16* l) {
  __builtin_amdgcn_global_load_lds(
      (const __attribute__((address_space(1))) unsigned int*)(const void*)g,
      (__attribute__((address_space(3))) unsigned int*)(void*)l,
      16, 0, 0);
}

// ---------------------------------------------------------------- convert + cumsum (fused)
__global__ __launch_bounds__(256) void k_conv_cum(const float* __restrict__ x,
                                                  const float* __restrict__ pw,
                                                  const float* __restrict__ ow,
                                                  const float* __restrict__ lam,
                                                  u16* __restrict__ xb,
                                                  u16* __restrict__ pwb,
                                                  u16* __restrict__ owb,
                                                  float* __restrict__ pos) {
  const int NX = M_ * D_ / 4, NP = N4_ * D_ / 4;
  int bid = blockIdx.x;
  int tid = threadIdx.x;
  if (bid < 9216) {
    int i = bid * 256 + tid;
    const float* src; u16* dst; int j;
    if (i < NX)            { src = x;  dst = xb;  j = i; }
    else if (i < NX + NP)  { src = pw; dst = pwb; j = i - NX; }
    else                   { src = ow; dst = owb; j = i - NX - NP; }
    float4 v = ((const float4*)src)[j];
    ushort4 o; o.x = f2bf(v.x); o.y = f2bf(v.y); o.z = f2bf(v.z); o.w = f2bf(v.w);
    ((ushort4*)dst)[j] = o;
  } else {
    int b = bid - 9216;
    const float* in = lam + (size_t)b * L_;
    float* out = pos + (size_t)b * L_;
    float loc[8], s = 0.0f;
#pragma unroll
    for (int i = 0; i < 8; ++i) { loc[i] = in[tid * 8 + i]; s += loc[i]; }
    __shared__ float sb[256];
    sb[tid] = s;
    __syncthreads();
    for (int off = 1; off < 256; off <<= 1) {
      float t = (tid >= off) ? sb[tid - off] : 0.0f;
      __syncthreads();
      sb[tid] += t;
      __syncthreads();
    }
    float run = sb[tid] - s;   // exclusive prefix
#pragma unroll
    for (int i = 0; i < 8; ++i) { run += loc[i]; out[tid * 8 + i] = run; }
  }
}

// ---------------------------------------------------------------- GEMM1: h = silu(x @ pw^T + pb), split u/v/q/k
__global__ __launch_bounds__(256, 4) void k_gemm1(const u16* __restrict__ A,
                                                  const u16* __restrict__ Bw,
                                                  const float* __restrict__ bias,
                                                  u16* __restrict__ hu, u16* __restrict__ hv,
                                                  u16* __restrict__ hq, u16* __restrict__ hk) {
  const int K = D_;
  int bn = blockIdx.x, bm = blockIdx.y, tid = threadIdx.x;
  int w = tid >> 6, lane = tid & 63, quad = lane >> 4, r16 = lane & 15;
  __shared__ __align__(16) u16 As[8192], Bs[8192];   // 2 buffers x 128x32
  const u16* gA = A  + (size_t)(bm * 128) * K;
  const u16* gB = Bw + (size_t)(bn * 128) * K;
  int srow = tid >> 2, sc = tid & 3;
#pragma unroll
  for (int s = 0; s < 2; ++s) {
    int row = s * 64 + srow;
    int q = (sc - (row >> 1)) & 3;
    gl2lds16(gA + (size_t)row * K + q * 8, As + s * 2048 + w * 512);
    gl2lds16(gB + (size_t)row * K + q * 8, Bs + s * 2048 + w * 512);
  }
  f32x4 acc[4][4] = {};
  int wm = w & 1, wn = w >> 1;
  const int rowb = wm * 64, colb = wn * 64;
  for (int n = 0; n < 32; ++n) {
    __syncthreads();                       // drains stage(n)
    if (n + 1 < 32) {
      int kt = (n + 1) * 32, pb = (n + 1) & 1;
#pragma unroll
      for (int s = 0; s < 2; ++s) {
        int row = s * 64 + srow;
        int q = (sc - (row >> 1)) & 3;
        gl2lds16(gA + (size_t)row * K + kt + q * 8, As + pb * 4096 + s * 2048 + w * 512);
        gl2lds16(gB + (size_t)row * K + kt + q * 8, Bs + pb * 4096 + s * 2048 + w * 512);
      }
    }
    const u16* Ab = As + (n & 1) * 4096;
    const u16* Bb = Bs + (n & 1) * 4096;
    short8v af[4], bf[4];
#pragma unroll
    for (int mi = 0; mi < 4; ++mi) {
      int row = rowb + mi * 16 + r16;
      af[mi] = *(const short8v*)(Ab + (row * 4 + ((quad + (row >> 1)) & 3)) * 8);
    }
#pragma unroll
    for (int ni = 0; ni < 4; ++ni) {
      int row = colb + ni * 16 + r16;
      bf[ni] = *(const short8v*)(Bb + (row * 4 + ((quad + (row >> 1)) & 3)) * 8);
    }
#pragma unroll
    for (int mi = 0; mi < 4; ++mi)
#pragma unroll
      for (int ni = 0; ni < 4; ++ni)
        acc[mi][ni] = __builtin_amdgcn_mfma_f32_16x16x32_bf16(af[mi], bf[ni], acc[mi][ni], 0, 0, 0);
  }
  int nb = (bn * 128) >> 10;                 // which of u/v/q/k
  u16* dst = (nb == 0) ? hu : (nb == 1) ? hv : (nb == 2) ? hq : hk;
  int cbase = (bn * 128) & 1023;
  int row0 = bm * 128 + rowb;
#pragma unroll
  for (int ni = 0; ni < 4; ++ni) {
    int gcol = bn * 128 + colb + ni * 16 + r16;
    int lcol = cbase + colb + ni * 16 + r16;
    float bb = bias[gcol];
#pragma unroll
    for (int mi = 0; mi < 4; ++mi)
#pragma unroll
      for (int r = 0; r < 4; ++r) {
        int row = row0 + mi * 16 + quad * 4 + r;
        dst[(size_t)row * D_ + lcol] = f2bf(siluf(acc[mi][ni][r] + bb));
      }
  }
}

// ---------------------------------------------------------------- RoPE + gates (+head_scale into Q) and V gate+transpose (fused)
__global__ __launch_bounds__(256) void k_rope_vt(const u16* __restrict__ hq, const u16* __restrict__ hk,
                                                 const u16* __restrict__ hv,
                                                 const float* __restrict__ pos,
                                                 const float* __restrict__ qg, const float* __restrict__ kg,
                                                 const float* __restrict__ vg,
                                                 const float* __restrict__ hsc,
                                                 u16* __restrict__ Qb, u16* __restrict__ Kb,
                                                 u16* __restrict__ Vtb) {
  int bid = blockIdx.x;
  int tid = threadIdx.x;
  if (bid < 2048) {
    int idx = bid * 256 + tid;   // (bh*2048 + l)*8 + j4
    int j4 = idx & 7;
    int l  = (idx >> 3) & 2047;
    int bh = idx >> 14;
    int b = bh >> 4, hh = bh & 15;
    int row = b * L_ + l;
    float p = pos[row];
    float qs = qg[(size_t)row * NH_ + hh] * hsc[hh];
    float kgv = kg[(size_t)row * NH_ + hh];
    const u16* hqr = hq + (size_t)row * D_ + hh * DH_ + j4 * 8;
    const u16* hkr = hk + (size_t)row * D_ + hh * DH_ + j4 * 8;
    short8v qv = *(const short8v*)hqr;
    short8v kv = *(const short8v*)hkr;
    size_t ob = ((size_t)bh * L_ + l) * DH_ + j4 * 4;
    u16 qeo[4], qoo[4], keo[4], koo[4];
#pragma unroll
    for (int t = 0; t < 4; ++t) {
      int j = j4 * 4 + t;
      float inv = __expf(-(float)j * 0.28782313662425574f);  // 10000^(-2j/64)
      float a = p * inv;
      float c, s;
      __sincosf(a, &s, &c);
      float qe = bf2f((u16)qv[2 * t]), qo = bf2f((u16)qv[2 * t + 1]);
      float ke = bf2f((u16)kv[2 * t]), ko = bf2f((u16)kv[2 * t + 1]);
      qeo[t] = f2bf((qe * c - qo * s) * qs);
      qoo[t] = f2bf((qe * s + qo * c) * qs);
      keo[t] = f2bf((ke * c - ko * s) * kgv);
      koo[t] = f2bf((ke * s + ko * c) * kgv);
    }
    *(ushort4*)(Qb + ob)      = make_ushort4(qeo[0], qeo[1], qeo[2], qeo[3]);
    *(ushort4*)(Qb + ob + 32) = make_ushort4(qoo[0], qoo[1], qoo[2], qoo[3]);
    *(ushort4*)(Kb + ob)      = make_ushort4(keo[0], keo[1], keo[2], keo[3]);
    *(ushort4*)(Kb + ob + 32) = make_ushort4(koo[0], koo[1], koo[2], koo[3]);
  } else {
    int b2 = bid - 2048;
    int lt = b2 & 31;           // l-tile
    int bh = b2 >> 5;
    int b = bh >> 4, hh = bh & 15;
    __shared__ u16 t[64][68];   // pad to break transpose conflicts
    {
      int r = tid >> 2, cg = tid & 3;
      int row = b * L_ + lt * 64 + r;
      float gv = vg[(size_t)row * NH_ + hh];
      const u16* src = hv + (size_t)row * D_ + hh * DH_ + cg * 16;
      short8v v0 = ((const short8v*)src)[0];
      short8v v1 = ((const short8v*)src)[1];
#pragma unroll
      for (int e = 0; e < 8; ++e) {
        t[r][cg * 16 + e]     = f2bf(bf2f((u16)v0[e]) * gv);
        t[r][cg * 16 + 8 + e] = f2bf(bf2f((u16)v1[e]) * gv);
      }
    }
    __syncthreads();
    {
      int d = tid >> 2, lg = tid & 3;
      short8v o0, o1;
#pragma unroll
      for (int e = 0; e < 8; ++e) o0[e] = (short)t[lg * 16 + e][d];
#pragma unroll
      for (int e = 0; e < 8; ++e) o1[e] = (short)t[lg * 16 + 8 + e][d];
      u16* dst = Vtb + ((size_t)bh * DH_ + d) * L_ + lt * 64 + lg * 16;
      ((short8v*)dst)[0] = o0;
      ((short8v*)dst)[1] = o1;
    }
  }
}

// ---------------------------------------------------------------- fused causal gated attention + u-multiply
// v8: barrier-free register-P (v7) with the occupancy/latency fixes:
//     - 16 i-rows per wave -> 4096 single-wave blocks = 16 waves/CU structural (2x v7 cap)
//     - one-slice software pipeline: V(s)+bias(s)+K(s+1) issued before compute of slice s
//     - longest-first + same-bh -> same-XCD ordering (id&7 round-robin)
__global__ __launch_bounds__(64, 4) void k_attn(const u16* __restrict__ Qb, const u16* __restrict__ Kb,
                                                const u16* __restrict__ Vtb, const float* __restrict__ tpb,
                                                const u16* __restrict__ hu, u16* __restrict__ A2) {
  int id = blockIdx.x;
  int xcd = id & 7, rr_ = id >> 3;
  int bh = xcd + 8 * (rr_ & 3);      // same-bh blocks land on same XCD (id%8 round-robin)
  int t  = 127 - (rr_ >> 2);         // 16-row i-tile, longest (t=127) first
  int b = bh >> 4, hh = bh & 15;
  int lane = threadIdx.x & 63, quad = lane >> 4, r16 = lane & 15;
  const size_t bhbase = (size_t)bh * L_ * DH_;
  const int irow = t * 16;
  const int gimax = irow + 15;
  const int ns = (t >> 1) + 1;       // number of 32-j slices
  // Q fragments (B-operand: n=i, k=d)
  const u16* qt = Qb + bhbase + (size_t)irow * DH_;
  short8v bq[2];
#pragma unroll
  for (int ks = 0; ks < 2; ++ks)
    bq[ks] = *(const short8v*)(qt + (size_t)r16 * DH_ + ks * 32 + quad * 8);
  // lane-base pointers
  const u16* Kln = Kb + bhbase + (size_t)r16 * DH_ + quad * 8;   // + j*DH_
  const u16* Vln = Vtb + bhbase + (size_t)r16 * L_ + quad * 8;   // + d16*16*L_ + jcol
  const float* bbase = tpb + ((size_t)(b * L_ + irow + r16)) * L_ + quad * 4;
  f32x4 accy[4] = {};
  // preload K(0): kc[st][half]
  short8v kc[2][2];
#pragma unroll
  for (int st = 0; st < 2; ++st) {
    kc[st][0] = *(const short8v*)(Kln + (size_t)(st * 16) * DH_);
    kc[st][1] = *(const short8v*)(Kln + (size_t)(st * 16) * DH_ + 32);
  }
  for (int s = 0; s < ns; ++s) {
    int jsl = s * 32;
    // ---- issue loads first: V(s), bias(s), K(s+1) — covered by this slice's compute
    short8v vb[4];
#pragma unroll
    for (int ni = 0; ni < 4; ++ni)
      vb[ni] = *(const short8v*)(Vln + (size_t)(ni * 16) * L_ + jsl);
    float4 bvv[2];
#pragma unroll
    for (int st = 0; st < 2; ++st)
      if (jsl + st * 16 <= gimax)
        bvv[st] = *(const float4*)(bbase + jsl + st * 16);
    short8v kn[2][2];
    bool more = (s + 1 < ns);
    if (more) {
      int jn = jsl + 32;
#pragma unroll
      for (int st = 0; st < 2; ++st) {
        kn[st][0] = *(const short8v*)(Kln + (size_t)(jn + st * 16) * DH_);
        kn[st][1] = *(const short8v*)(Kln + (size_t)(jn + st * 16) * DH_ + 32);
      }
    }
    // ---- QK for the slice's two 16-j subtiles
    unsigned int W[2][2];
#pragma unroll
    for (int st = 0; st < 2; ++st) {
      int jlo = jsl + st * 16;
      unsigned int p01 = 0, p23 = 0;
      if (jlo <= gimax) {                    // subtile touched (wave-uniform)
        f32x4 acc = {};
        acc = __builtin_amdgcn_mfma_f32_16x16x32_bf16(kc[st][0], bq[0], acc, 0, 0, 0);
        acc = __builtin_amdgcn_mfma_f32_16x16x32_bf16(kc[st][1], bq[1], acc, 0, 0, 0);
        float4 bvx = bvv[st];
        if (jlo + 15 <= irow) {              // fully unmasked subtile (majority)
          p01 = pk_bf16(siluf(fmaf(4.0f, bvx.x, acc[0])), siluf(fmaf(4.0f, bvx.y, acc[1])));
          p23 = pk_bf16(siluf(fmaf(4.0f, bvx.z, acc[2])), siluf(fmaf(4.0f, bvx.w, acc[3])));
        } else {                             // diagonal subtile: per-element mask
          int gi = irow + r16;
          int j0 = jlo + quad * 4;
          float v0 = (j0     <= gi) ? siluf(fmaf(4.0f, bvx.x, acc[0])) : 0.0f;
          float v1 = (j0 + 1 <= gi) ? siluf(fmaf(4.0f, bvx.y, acc[1])) : 0.0f;
          float v2 = (j0 + 2 <= gi) ? siluf(fmaf(4.0f, bvx.z, acc[2])) : 0.0f;
          float v3 = (j0 + 3 <= gi) ? siluf(fmaf(4.0f, bvx.w, acc[3])) : 0.0f;
          p01 = pk_bf16(v0, v1);
          p23 = pk_bf16(v2, v3);
        }
      }
      W[st][0] = p01; W[st][1] = p23;
    }
    // ---- redistribute to PV A-fragment
    unsigned int paw[4];
#pragma unroll
    for (int p = 0; p < 2; ++p) {
      unsigned int x = W[0][p], y = W[1][p];
      asm("v_permlane32_swap_b32 %0, %1" : "+v"(x), "+v"(y));
      asm("v_permlane16_swap_b32 %0, %1" : "+v"(x), "+v"(y));
      paw[p]     = x;
      paw[2 + p] = y;
    }
    union { unsigned int u[4]; short8v s8; } pu;
    pu.u[0] = paw[0]; pu.u[1] = paw[1]; pu.u[2] = paw[2]; pu.u[3] = paw[3];
    // ---- PV for this slice
#pragma unroll
    for (int ni = 0; ni < 4; ++ni)
      accy[ni] = __builtin_amdgcn_mfma_f32_16x16x32_bf16(pu.s8, vb[ni], accy[ni], 0, 0, 0);
    if (more) {
#pragma unroll
      for (int st = 0; st < 2; ++st) { kc[st][0] = kn[st][0]; kc[st][1] = kn[st][1]; }
    }
  }
  // final epilogue: y * u -> A2 (b, l, h*64+d) bf16
  const u16* hup = hu + ((size_t)(b * L_ + irow)) * D_ + hh * DH_;
  u16* a2p = A2 + ((size_t)(b * L_ + irow)) * D_ + hh * DH_;
#pragma unroll
  for (int ni = 0; ni < 4; ++ni) {
    int d = ni * 16 + r16;
#pragma unroll
    for (int rreg = 0; rreg < 4; ++rreg) {
      int lr = quad * 4 + rreg;
      float u = bf2f(hup[(size_t)lr * D_ + d]);
      a2p[(size_t)lr * D_ + d] = f2bf(accy[ni][rreg] * u);
    }
  }
}

// ---------------------------------------------------------------- GEMM2: r = (y*u) @ ow^T + ob + x
__global__ __launch_bounds__(256, 4) void k_gemm2(const u16* __restrict__ A,
                                                  const u16* __restrict__ Bw,
                                                  const float* __restrict__ bias,
                                                  const float* __restrict__ xres,
                                                  float* __restrict__ out) {
  const int K = D_;
  int bn = blockIdx.x, bm = blockIdx.y, tid = threadIdx.x;
  int w = tid >> 6, lane = tid & 63, quad = lane >> 4, r16 = lane & 15;
  __shared__ __align__(16) u16 As[8192], Bs[8192];
  const u16* gA = A  + (size_t)(bm * 128) * K;
  const u16* gB = Bw + (size_t)(bn * 128) * K;
  int srow = tid >> 2, sc = tid & 3;
#pragma unroll
  for (int s = 0; s < 2; ++s) {
    int row = s * 64 + srow;
    int q = (sc - (row >> 1)) & 3;
    gl2lds16(gA + (size_t)row * K + q * 8, As + s * 2048 + w * 512);
    gl2lds16(gB + (size_t)row * K + q * 8, Bs + s * 2048 + w * 512);
  }
  f32x4 acc[4][4] = {};
  int wm = w & 1, wn = w >> 1;
  const int rowb = wm * 64, colb = wn * 64;
  for (int n = 0; n < 32; ++n) {
    __syncthreads();
    if (n + 1 < 32) {
      int kt = (n + 1) * 32, pb = (n + 1) & 1;
#pragma unroll
      for (int s = 0; s < 2; ++s) {
        int row = s * 64 + srow;
        int q = (sc - (row >> 1)) & 3;
        gl2lds16(gA + (size_t)row * K + kt + q * 8, As + pb * 4096 + s * 2048 + w * 512);
        gl2lds16(gB + (size_t)row * K + kt + q * 8, Bs + pb * 4096 + s * 2048 + w * 512);
      }
    }
    const u16* Ab = As + (n & 1) * 4096;
    const u16* Bb = Bs + (n & 1) * 4096;
    short8v af[4], bf[4];
#pragma unroll
    for (int mi = 0; mi < 4; ++mi) {
      int row = rowb + mi * 16 + r16;
      af[mi] = *(const short8v*)(Ab + (row * 4 + ((quad + (row >> 1)) & 3)) * 8);
    }
#pragma unroll
    for (int ni = 0; ni < 4; ++ni) {
      int row = colb + ni * 16 + r16;
      bf[ni] = *(const short8v*)(Bb + (row * 4 + ((quad + (row >> 1)) & 3)) * 8);
    }
#pragma unroll
    for (int mi = 0; mi < 4; ++mi)
#pragma unroll
      for (int ni = 0; ni < 4; ++ni)
        acc[mi][ni] = __builtin_amdgcn_mfma_f32_16x16x32_bf16(af[mi], bf[ni], acc[mi][ni], 0, 0, 0);
  }
  int row0 = bm * 128 + rowb, col0 = bn * 128 + colb;
#pragma unroll
  for (int ni = 0; ni < 4; ++ni) {
    int col = col0 + ni * 16 + r16;
    float bb = bias[col];
#pragma unroll
    for (int mi = 0; mi < 4; ++mi)
#pragma unroll
      for (int r = 0; r < 4; ++r) {
        int row = row0 + mi * 16 + quad * 4 + r;
        out[(size_t)row * D_ + col] = acc[mi][ni][r] + bb + xres[(size_t)row * D_ + col];
      }
  }
}

// ---------------------------------------------------------------- LayerNorm (in place on d_out)
__global__ __launch_bounds__(256) void k_ln(float* __restrict__ r,
                                            const float* __restrict__ g,
                                            const float* __restrict__ be) {
  int row = blockIdx.x, tid = threadIdx.x;
  float* pr = r + (size_t)row * D_;
  __shared__ float s1[4], s2[4];
  float v[4];
#pragma unroll
  for (int i = 0; i < 4; ++i) v[i] = pr[i * 256 + tid];
  float s = v[0] + v[1] + v[2] + v[3];
#pragma unroll
  for (int o = 32; o > 0; o >>= 1) s += __shfl_down(s, o, 64);
  if ((tid & 63) == 0) s1[tid >> 6] = s;
  __syncthreads();
  float mu = (s1[0] + s1[1] + s1[2] + s1[3]) * (1.0f / D_);
  float d = 0.0f;
#pragma unroll
  for (int i = 0; i < 4; ++i) { float t = v[i] - mu; d += t * t; }
#pragma unroll
  for (int o = 32; o > 0; o >>= 1) d += __shfl_down(d, o, 64);
  if ((tid & 63) == 0) s2[tid >> 6] = d;
  __syncthreads();
  float var = (s2[0] + s2[1] + s2[2] + s2[3]) * (1.0f / D_);
  float inv = rsqrtf(var + 1e-5f);
#pragma unroll
  for (int i = 0; i < 4; ++i) {
    int c = i * 256 + tid;
    pr[c] = (v[i] - mu) * inv * g[c] + be[c];
  }
}

// ---------------------------------------------------------------- launch
extern "C" void kernel_launch(void* const* d_in, const int* in_sizes, int n_in,
                              void* d_out, int out_size, void* d_ws, size_t ws_size,
                              hipStream_t stream) {
  const float* x   = (const float*)d_in[0];
  // d_in[1] attn_mask: deterministic causal tril -> not read
  // d_in[2] ts: unused by reference
  const float* lam = (const float*)d_in[3];
  const float* qg  = (const float*)d_in[4];
  const float* kg  = (const float*)d_in[5];
  const float* vg  = (const float*)d_in[6];
  const float* tpb = (const float*)d_in[7];
  const float* pw  = (const float*)d_in[8];
  const float* pb  = (const float*)d_in[9];
  const float* ow  = (const float*)d_in[10];
  const float* ob  = (const float*)d_in[11];
  const float* hsc = (const float*)d_in[12];
  const float* lng = (const float*)d_in[13];
  const float* lnb = (const float*)d_in[14];
  float* out = (float*)d_out;

  char* ws = (char*)d_ws;
  // layout (bytes). aliasing: Qb<-xb, Kb<-pwb, Vtb<-hq, A2<-hk (all after last read)
  u16* xb   = (u16*)(ws + 0);          // 8 MB   x bf16
  u16* pwb  = (u16*)(ws + 8388608);    // 8 MB   proj_w bf16
  u16* owb  = (u16*)(ws + 16777216);   // 2 MB   out_w bf16
  u16* hu   = (u16*)(ws + 18874368);   // 8 MB
  u16* hv   = (u16*)(ws + 27262976);   // 8 MB
  u16* hq   = (u16*)(ws + 35651584);   // 8 MB
  u16* hk   = (u16*)(ws + 44040192);   // 8 MB
  float* pos = (float*)(ws + 52428800); // 16 KB
  u16* Qb  = xb;
  u16* Kb  = pwb;
  u16* Vtb = hq;
  u16* A2  = hk;

  k_conv_cum<<<9218, 256, 0, stream>>>(x, pw, ow, lam, xb, pwb, owb, pos);
  k_gemm1<<<dim3(32, 32), 256, 0, stream>>>(xb, pwb, pb, hu, hv, hq, hk);
  k_rope_vt<<<3072, 256, 0, stream>>>(hq, hk, hv, pos, qg, kg, vg, hsc, Qb, Kb, Vtb);
  k_attn<<<4096, 64, 0, stream>>>(Qb, Kb, Vtb, tpb, hu, A2);
  k_gemm2<<<dim3(8, 32), 256, 0, stream>>>(A2, owb, ob, x, out);
  k_ln<<<4096, 256, 0, stream>>>(out, lng, lnb);
}

// Round 5
// 296.591 us; speedup vs baseline: 1.2994x; 1.2994x over previous
//
#include <hip/hip_runtime.h>
#include <cstdint>
#include <cstddef>

typedef unsigned short u16;
typedef __attribute__((ext_vector_type(8))) short short8v;   // 8 x bf16 (4 VGPRs)
typedef __attribute__((ext_vector_type(4))) float f32x4;

#define B_   2
#define L_   2048
#define D_   1024
#define NH_  16
#define DH_  64
#define M_   (B_*L_)      /* 4096 */
#define N4_  (4*D_)       /* 4096 */

__device__ __forceinline__ float bf2f(u16 u) {
  union { float f; unsigned int i; } v; v.i = ((unsigned int)u) << 16; return v.f;
}
__device__ __forceinline__ u16 f2bf(float f) {
  union { float f; unsigned int i; } v; v.f = f;
  unsigned int x = v.i;
  return (u16)((x + 0x7fffu + ((x >> 16) & 1u)) >> 16);   // RNE
}
__device__ __forceinline__ unsigned int pk_bf16(float a, float b) {
#if __has_builtin(__builtin_amdgcn_cvt_pk_bf16_f32)
  auto r = __builtin_amdgcn_cvt_pk_bf16_f32(a, b);
  union { decltype(r) v; unsigned int u; } c; c.v = r; return c.u;
#else
  unsigned int r;
  asm("v_cvt_pk_bf16_f32 %0, %1, %2" : "=v"(r) : "v"(a), "v"(b));
  return r;
#endif
}
// silu via v_rcp_f32 (approx rcp, ~1ulp) instead of IEEE divide
__device__ __forceinline__ float siluf(float x) {
  return x * __builtin_amdgcn_rcpf(1.0f + __expf(-x));
}

// async global->LDS, 16B per lane. LDS dest = wave-uniform base + lane*16.
__device__ __forceinline__ void gl2lds16(const u16* g, u16* l) {
  __builtin_amdgcn_global_load_lds(
      (const __attribute__((address_space(1))) unsigned int*)(const void*)g,
      (__attribute__((address_space(3))) unsigned int*)(void*)l,
      16, 0, 0);
}

// ---------------------------------------------------------------- convert + cumsum (fused)
__global__ __launch_bounds__(256) void k_conv_cum(const float* __restrict__ x,
                                                  const float* __restrict__ pw,
                                                  const float* __restrict__ ow,
                                                  const float* __restrict__ lam,
                                                  u16* __restrict__ xb,
                                                  u16* __restrict__ pwb,
                                                  u16* __restrict__ owb,
                                                  float* __restrict__ pos) {
  const int NX = M_ * D_ / 4, NP = N4_ * D_ / 4;
  int bid = blockIdx.x;
  int tid = threadIdx.x;
  if (bid < 9216) {
    int i = bid * 256 + tid;
    const float* src; u16* dst; int j;
    if (i < NX)            { src = x;  dst = xb;  j = i; }
    else if (i < NX + NP)  { src = pw; dst = pwb; j = i - NX; }
    else                   { src = ow; dst = owb; j = i - NX - NP; }
    float4 v = ((const float4*)src)[j];
    ushort4 o; o.x = f2bf(v.x); o.y = f2bf(v.y); o.z = f2bf(v.z); o.w = f2bf(v.w);
    ((ushort4*)dst)[j] = o;
  } else {
    int b = bid - 9216;
    const float* in = lam + (size_t)b * L_;
    float* out = pos + (size_t)b * L_;
    float loc[8], s = 0.0f;
#pragma unroll
    for (int i = 0; i < 8; ++i) { loc[i] = in[tid * 8 + i]; s += loc[i]; }
    __shared__ float sb[256];
    sb[tid] = s;
    __syncthreads();
    for (int off = 1; off < 256; off <<= 1) {
      float t = (tid >= off) ? sb[tid - off] : 0.0f;
      __syncthreads();
      sb[tid] += t;
      __syncthreads();
    }
    float run = sb[tid] - s;   // exclusive prefix
#pragma unroll
    for (int i = 0; i < 8; ++i) { run += loc[i]; out[tid * 8 + i] = run; }
  }
}

// ---------------------------------------------------------------- GEMM1: h = silu(x @ pw^T + pb), split u/v/q/k
__global__ __launch_bounds__(256, 4) void k_gemm1(const u16* __restrict__ A,
                                                  const u16* __restrict__ Bw,
                                                  const float* __restrict__ bias,
                                                  u16* __restrict__ hu, u16* __restrict__ hv,
                                                  u16* __restrict__ hq, u16* __restrict__ hk) {
  const int K = D_;
  int bn = blockIdx.x, bm = blockIdx.y, tid = threadIdx.x;
  int w = tid >> 6, lane = tid & 63, quad = lane >> 4, r16 = lane & 15;
  __shared__ __align__(16) u16 As[8192], Bs[8192];   // 2 buffers x 128x32
  const u16* gA = A  + (size_t)(bm * 128) * K;
  const u16* gB = Bw + (size_t)(bn * 128) * K;
  int srow = tid >> 2, sc = tid & 3;
#pragma unroll
  for (int s = 0; s < 2; ++s) {
    int row = s * 64 + srow;
    int q = (sc - (row >> 1)) & 3;
    gl2lds16(gA + (size_t)row * K + q * 8, As + s * 2048 + w * 512);
    gl2lds16(gB + (size_t)row * K + q * 8, Bs + s * 2048 + w * 512);
  }
  f32x4 acc[4][4] = {};
  int wm = w & 1, wn = w >> 1;
  const int rowb = wm * 64, colb = wn * 64;
  for (int n = 0; n < 32; ++n) {
    __syncthreads();                       // drains stage(n)
    if (n + 1 < 32) {
      int kt = (n + 1) * 32, pb = (n + 1) & 1;
#pragma unroll
      for (int s = 0; s < 2; ++s) {
        int row = s * 64 + srow;
        int q = (sc - (row >> 1)) & 3;
        gl2lds16(gA + (size_t)row * K + kt + q * 8, As + pb * 4096 + s * 2048 + w * 512);
        gl2lds16(gB + (size_t)row * K + kt + q * 8, Bs + pb * 4096 + s * 2048 + w * 512);
      }
    }
    const u16* Ab = As + (n & 1) * 4096;
    const u16* Bb = Bs + (n & 1) * 4096;
    short8v af[4], bf[4];
#pragma unroll
    for (int mi = 0; mi < 4; ++mi) {
      int row = rowb + mi * 16 + r16;
      af[mi] = *(const short8v*)(Ab + (row * 4 + ((quad + (row >> 1)) & 3)) * 8);
    }
#pragma unroll
    for (int ni = 0; ni < 4; ++ni) {
      int row = colb + ni * 16 + r16;
      bf[ni] = *(const short8v*)(Bb + (row * 4 + ((quad + (row >> 1)) & 3)) * 8);
    }
#pragma unroll
    for (int mi = 0; mi < 4; ++mi)
#pragma unroll
      for (int ni = 0; ni < 4; ++ni)
        acc[mi][ni] = __builtin_amdgcn_mfma_f32_16x16x32_bf16(af[mi], bf[ni], acc[mi][ni], 0, 0, 0);
  }
  int nb = (bn * 128) >> 10;                 // which of u/v/q/k
  u16* dst = (nb == 0) ? hu : (nb == 1) ? hv : (nb == 2) ? hq : hk;
  int cbase = (bn * 128) & 1023;
  int row0 = bm * 128 + rowb;
#pragma unroll
  for (int ni = 0; ni < 4; ++ni) {
    int gcol = bn * 128 + colb + ni * 16 + r16;
    int lcol = cbase + colb + ni * 16 + r16;
    float bb = bias[gcol];
#pragma unroll
    for (int mi = 0; mi < 4; ++mi)
#pragma unroll
      for (int r = 0; r < 4; ++r) {
        int row = row0 + mi * 16 + quad * 4 + r;
        dst[(size_t)row * D_ + lcol] = f2bf(siluf(acc[mi][ni][r] + bb));
      }
  }
}

// ---------------------------------------------------------------- RoPE + gates (+head_scale into Q) and V gate+transpose (fused)
__global__ __launch_bounds__(256) void k_rope_vt(const u16* __restrict__ hq, const u16* __restrict__ hk,
                                                 const u16* __restrict__ hv,
                                                 const float* __restrict__ pos,
                                                 const float* __restrict__ qg, const float* __restrict__ kg,
                                                 const float* __restrict__ vg,
                                                 const float* __restrict__ hsc,
                                                 u16* __restrict__ Qb, u16* __restrict__ Kb,
                                                 u16* __restrict__ Vtb) {
  int bid = blockIdx.x;
  int tid = threadIdx.x;
  if (bid < 2048) {
    int idx = bid * 256 + tid;   // (bh*2048 + l)*8 + j4
    int j4 = idx & 7;
    int l  = (idx >> 3) & 2047;
    int bh = idx >> 14;
    int b = bh >> 4, hh = bh & 15;
    int row = b * L_ + l;
    float p = pos[row];
    float qs = qg[(size_t)row * NH_ + hh] * hsc[hh];
    float kgv = kg[(size_t)row * NH_ + hh];
    const u16* hqr = hq + (size_t)row * D_ + hh * DH_ + j4 * 8;
    const u16* hkr = hk + (size_t)row * D_ + hh * DH_ + j4 * 8;
    short8v qv = *(const short8v*)hqr;
    short8v kv = *(const short8v*)hkr;
    size_t ob = ((size_t)bh * L_ + l) * DH_ + j4 * 4;
    u16 qeo[4], qoo[4], keo[4], koo[4];
#pragma unroll
    for (int t = 0; t < 4; ++t) {
      int j = j4 * 4 + t;
      float inv = __expf(-(float)j * 0.28782313662425574f);  // 10000^(-2j/64)
      float a = p * inv;
      float c, s;
      __sincosf(a, &s, &c);
      float qe = bf2f((u16)qv[2 * t]), qo = bf2f((u16)qv[2 * t + 1]);
      float ke = bf2f((u16)kv[2 * t]), ko = bf2f((u16)kv[2 * t + 1]);
      qeo[t] = f2bf((qe * c - qo * s) * qs);
      qoo[t] = f2bf((qe * s + qo * c) * qs);
      keo[t] = f2bf((ke * c - ko * s) * kgv);
      koo[t] = f2bf((ke * s + ko * c) * kgv);
    }
    *(ushort4*)(Qb + ob)      = make_ushort4(qeo[0], qeo[1], qeo[2], qeo[3]);
    *(ushort4*)(Qb + ob + 32) = make_ushort4(qoo[0], qoo[1], qoo[2], qoo[3]);
    *(ushort4*)(Kb + ob)      = make_ushort4(keo[0], keo[1], keo[2], keo[3]);
    *(ushort4*)(Kb + ob + 32) = make_ushort4(koo[0], koo[1], koo[2], koo[3]);
  } else {
    int b2 = bid - 2048;
    int lt = b2 & 31;           // l-tile
    int bh = b2 >> 5;
    int b = bh >> 4, hh = bh & 15;
    __shared__ u16 t[64][68];   // pad to break transpose conflicts
    {
      int r = tid >> 2, cg = tid & 3;
      int row = b * L_ + lt * 64 + r;
      float gv = vg[(size_t)row * NH_ + hh];
      const u16* src = hv + (size_t)row * D_ + hh * DH_ + cg * 16;
      short8v v0 = ((const short8v*)src)[0];
      short8v v1 = ((const short8v*)src)[1];
#pragma unroll
      for (int e = 0; e < 8; ++e) {
        t[r][cg * 16 + e]     = f2bf(bf2f((u16)v0[e]) * gv);
        t[r][cg * 16 + 8 + e] = f2bf(bf2f((u16)v1[e]) * gv);
      }
    }
    __syncthreads();
    {
      int d = tid >> 2, lg = tid & 3;
      short8v o0, o1;
#pragma unroll
      for (int e = 0; e < 8; ++e) o0[e] = (short)t[lg * 16 + e][d];
#pragma unroll
      for (int e = 0; e < 8; ++e) o1[e] = (short)t[lg * 16 + 8 + e][d];
      u16* dst = Vtb + ((size_t)bh * DH_ + d) * L_ + lt * 64 + lg * 16;
      ((short8v*)dst)[0] = o0;
      ((short8v*)dst)[1] = o1;
    }
  }
}

// ---------------------------------------------------------------- fused causal gated attention + u-multiply
// v9: v6's proven LDS-staged / register-P structure (86us), resized for balance + cheap sync:
//     32-row tiles, 2 waves/block, KVBLK=64, LDS 16KB (Ks 8KB + Vs 8KB).
//     2048 blocks = 8 blocks/CU x 2 waves = 16 waves/CU structural; barriers sync only 2 waves;
//     triangular imbalance at 64-tier granularity, longest-first, same-bh -> same-XCD.
//     Same staging swizzle + barrier invariants as v6:
//       b1: K(jt) drained, Vs free -> stage V(jt); QK from Ks
//       b2: V(jt) drained, Ks free -> stage K(jt+1), prefetch bias(jt+1); PV from Vs
__global__ __launch_bounds__(128, 4) void k_attn(const u16* __restrict__ Qb, const u16* __restrict__ Kb,
                                                 const u16* __restrict__ Vtb, const float* __restrict__ tpb,
                                                 const u16* __restrict__ hu, u16* __restrict__ A2) {
  int id = blockIdx.x;
  int bh = (id & 7) + 8 * ((id >> 3) & 3);   // same-bh blocks land on same XCD (id%8 round-robin)
  int t  = 63 - (id >> 5);                   // 32-row i-tile, longest (t=63) first
  int b = bh >> 4, hh = bh & 15;
  int tid = threadIdx.x, w = tid >> 6, lane = tid & 63, quad = lane >> 4, r16 = lane & 15;
  __shared__ __align__(16) u16 Ks[4096];   // 2 d-halves x (64j x 32d), content-rotated
  __shared__ __align__(16) u16 Vs[4096];   // 2 j-slices x (64d x 32j), content-rotated
  const size_t bhbase = (size_t)bh * L_ * DH_;
  const int irow = t * 32 + w * 16;        // wave's 16 i-rows
  const int gimax_w = irow + 15;
  const int jmax = t >> 1;                 // 64-j iterations cover j <= t*32+31
  // Q fragment (B-operand: n=i, k=d)
  const u16* qt = Qb + bhbase + (size_t)irow * DH_;
  short8v bq[2];
#pragma unroll
  for (int ks = 0; ks < 2; ++ks)
    bq[ks] = *(const short8v*)(qt + (size_t)r16 * DH_ + ks * 32 + quad * 8);
  int srow = tid >> 2, sc = tid & 3;       // staging: srow 0..31, quad-slot 0..3
  // stage K(0)
#pragma unroll
  for (int s = 0; s < 4; ++s) {
    int half = s & 1, h = s >> 1;
    int row = half * 32 + srow;            // j-row 0..63
    int q = (sc - (row >> 1)) & 3;
    gl2lds16(Kb + bhbase + (size_t)row * DH_ + h * 32 + q * 8,
             Ks + h * 2048 + half * 1024 + w * 512);
  }
  // bias row pointer (lane's own i-row); prefetch bias(0)
  const float* bbase = tpb + ((size_t)(b * L_ + irow + r16)) * L_ + quad * 4;
  float4 bv[4];
#pragma unroll
  for (int tj = 0; tj < 4; ++tj)
    if (tj * 16 <= gimax_w) bv[tj] = *(const float4*)(bbase + tj * 16);
  f32x4 accy[4] = {};
  for (int jt = 0; jt <= jmax; ++jt) {
    __syncthreads();   // b1: K(jt)+bias(jt) drained; Vs free (prev PV done)
    // stage V(jt)
#pragma unroll
    for (int s = 0; s < 4; ++s) {
      int half = s & 1, sl = s >> 1;
      int row = half * 32 + srow;          // d-row 0..63
      int q = (sc - (row >> 1)) & 3;
      gl2lds16(Vtb + bhbase + (size_t)row * L_ + jt * 64 + sl * 32 + q * 8,
               Vs + sl * 2048 + half * 1024 + w * 512);
    }
    // ---- QK over 4 16-j subtiles (S^T = K.Q^T); bias+silu+mask+pack
    unsigned int W[4][2];
#pragma unroll
    for (int tj = 0; tj < 4; ++tj) {
      int jlo = jt * 64 + tj * 16;
      unsigned int p01 = 0, p23 = 0;
      if (jlo <= gimax_w) {                // subtile touched (wave-uniform)
        int jr = tj * 16 + r16;
        int sw = (quad + (jr >> 1)) & 3;
        short8v ak0 = *(const short8v*)(Ks + jr * 32 + sw * 8);
        short8v ak1 = *(const short8v*)(Ks + 2048 + jr * 32 + sw * 8);
        f32x4 acc = {};
        acc = __builtin_amdgcn_mfma_f32_16x16x32_bf16(ak0, bq[0], acc, 0, 0, 0);
        acc = __builtin_amdgcn_mfma_f32_16x16x32_bf16(ak1, bq[1], acc, 0, 0, 0);
        float4 bvx = bv[tj];
        if (jlo + 15 <= irow) {            // fully unmasked subtile (majority)
          p01 = pk_bf16(siluf(fmaf(4.0f, bvx.x, acc[0])), siluf(fmaf(4.0f, bvx.y, acc[1])));
          p23 = pk_bf16(siluf(fmaf(4.0f, bvx.z, acc[2])), siluf(fmaf(4.0f, bvx.w, acc[3])));
        } else {                           // diagonal subtile: per-element mask
          int gi = irow + r16;
          int j0 = jlo + quad * 4;
          float v0 = (j0     <= gi) ? siluf(fmaf(4.0f, bvx.x, acc[0])) : 0.0f;
          float v1 = (j0 + 1 <= gi) ? siluf(fmaf(4.0f, bvx.y, acc[1])) : 0.0f;
          float v2 = (j0 + 2 <= gi) ? siluf(fmaf(4.0f, bvx.z, acc[2])) : 0.0f;
          float v3 = (j0 + 3 <= gi) ? siluf(fmaf(4.0f, bvx.w, acc[3])) : 0.0f;
          p01 = pk_bf16(v0, v1);
          p23 = pk_bf16(v2, v3);
        }
      }
      W[tj][0] = p01; W[tj][1] = p23;
    }
    __syncthreads();   // b2: V(jt) drained; all waves done reading Ks(jt)
    // stage K(jt+1) and prefetch bias(jt+1) (drain at next b1, covered by PV)
    if (jt < jmax) {
      const size_t kb = bhbase + (size_t)(jt + 1) * 64 * DH_;
#pragma unroll
      for (int s = 0; s < 4; ++s) {
        int half = s & 1, h = s >> 1;
        int row = half * 32 + srow;
        int q = (sc - (row >> 1)) & 3;
        gl2lds16(Kb + kb + (size_t)row * DH_ + h * 32 + q * 8,
                 Ks + h * 2048 + half * 1024 + w * 512);
      }
      int jn = (jt + 1) * 64;
#pragma unroll
      for (int tj = 0; tj < 4; ++tj)
        if (jn + tj * 16 <= gimax_w) bv[tj] = *(const float4*)(bbase + jn + tj * 16);
    }
    // ---- redistribute subtile pairs to PV A-fragments: paw[k2]
    unsigned int paw[2][4];
#pragma unroll
    for (int k2 = 0; k2 < 2; ++k2)
#pragma unroll
      for (int p = 0; p < 2; ++p) {
        unsigned int x = W[2 * k2][p], y = W[2 * k2 + 1][p];
        asm("v_permlane32_swap_b32 %0, %1" : "+v"(x), "+v"(y));
        asm("v_permlane16_swap_b32 %0, %1" : "+v"(x), "+v"(y));
        paw[k2][p]     = x;
        paw[k2][2 + p] = y;
      }
    // ---- PV: register P x Vs
#pragma unroll
    for (int k2 = 0; k2 < 2; ++k2) {
      if (jt * 64 + k2 * 32 > gimax_w) continue;   // wave-uniform slice skip
      union { unsigned int u[4]; short8v s8; } pu;
      pu.u[0] = paw[k2][0]; pu.u[1] = paw[k2][1]; pu.u[2] = paw[k2][2]; pu.u[3] = paw[k2][3];
#pragma unroll
      for (int ni = 0; ni < 4; ++ni) {
        int vr = ni * 16 + r16;
        int sw = (quad + (vr >> 1)) & 3;
        short8v vb = *(const short8v*)(Vs + k2 * 2048 + vr * 32 + sw * 8);
        accy[ni] = __builtin_amdgcn_mfma_f32_16x16x32_bf16(pu.s8, vb, accy[ni], 0, 0, 0);
      }
    }
  }
  // final epilogue: y * u -> A2 (b, l, h*64+d) bf16
  const u16* hup = hu + ((size_t)(b * L_ + irow)) * D_ + hh * DH_;
  u16* a2p = A2 + ((size_t)(b * L_ + irow)) * D_ + hh * DH_;
#pragma unroll
  for (int ni = 0; ni < 4; ++ni) {
    int d = ni * 16 + r16;
#pragma unroll
    for (int rreg = 0; rreg < 4; ++rreg) {
      int lr = quad * 4 + rreg;
      float u = bf2f(hup[(size_t)lr * D_ + d]);
      a2p[(size_t)lr * D_ + d] = f2bf(accy[ni][rreg] * u);
    }
  }
}

// ---------------------------------------------------------------- GEMM2: r = (y*u) @ ow^T + ob + x
__global__ __launch_bounds__(256, 4) void k_gemm2(const u16* __restrict__ A,
                                                  const u16* __restrict__ Bw,
                                                  const float* __restrict__ bias,
                                                  const float* __restrict__ xres,
                                                  float* __restrict__ out) {
  const int K = D_;
  int bn = blockIdx.x, bm = blockIdx.y, tid = threadIdx.x;
  int w = tid >> 6, lane = tid & 63, quad = lane >> 4, r16 = lane & 15;
  __shared__ __align__(16) u16 As[8192], Bs[8192];
  const u16* gA = A  + (size_t)(bm * 128) * K;
  const u16* gB = Bw + (size_t)(bn * 128) * K;
  int srow = tid >> 2, sc = tid & 3;
#pragma unroll
  for (int s = 0; s < 2; ++s) {
    int row = s * 64 + srow;
    int q = (sc - (row >> 1)) & 3;
    gl2lds16(gA + (size_t)row * K + q * 8, As + s * 2048 + w * 512);
    gl2lds16(gB + (size_t)row * K + q * 8, Bs + s * 2048 + w * 512);
  }
  f32x4 acc[4][4] = {};
  int wm = w & 1, wn = w >> 1;
  const int rowb = wm * 64, colb = wn * 64;
  for (int n = 0; n < 32; ++n) {
    __syncthreads();
    if (n + 1 < 32) {
      int kt = (n + 1) * 32, pb = (n + 1) & 1;
#pragma unroll
      for (int s = 0; s < 2; ++s) {
        int row = s * 64 + srow;
        int q = (sc - (row >> 1)) & 3;
        gl2lds16(gA + (size_t)row * K + kt + q * 8, As + pb * 4096 + s * 2048 + w * 512);
        gl2lds16(gB + (size_t)row * K + kt + q * 8, Bs + pb * 4096 + s * 2048 + w * 512);
      }
    }
    const u16* Ab = As + (n & 1) * 4096;
    const u16* Bb = Bs + (n & 1) * 4096;
    short8v af[4], bf[4];
#pragma unroll
    for (int mi = 0; mi < 4; ++mi) {
      int row = rowb + mi * 16 + r16;
      af[mi] = *(const short8v*)(Ab + (row * 4 + ((quad + (row >> 1)) & 3)) * 8);
    }
#pragma unroll
    for (int ni = 0; ni < 4; ++ni) {
      int row = colb + ni * 16 + r16;
      bf[ni] = *(const short8v*)(Bb + (row * 4 + ((quad + (row >> 1)) & 3)) * 8);
    }
#pragma unroll
    for (int mi = 0; mi < 4; ++mi)
#pragma unroll
      for (int ni = 0; ni < 4; ++ni)
        acc[mi][ni] = __builtin_amdgcn_mfma_f32_16x16x32_bf16(af[mi], bf[ni], acc[mi][ni], 0, 0, 0);
  }
  int row0 = bm * 128 + rowb, col0 = bn * 128 + colb;
#pragma unroll
  for (int ni = 0; ni < 4; ++ni) {
    int col = col0 + ni * 16 + r16;
    float bb = bias[col];
#pragma unroll
    for (int mi = 0; mi < 4; ++mi)
#pragma unroll
      for (int r = 0; r < 4; ++r) {
        int row = row0 + mi * 16 + quad * 4 + r;
        out[(size_t)row * D_ + col] = acc[mi][ni][r] + bb + xres[(size_t)row * D_ + col];
      }
  }
}

// ---------------------------------------------------------------- LayerNorm (in place on d_out)
__global__ __launch_bounds__(256) void k_ln(float* __restrict__ r,
                                            const float* __restrict__ g,
                                            const float* __restrict__ be) {
  int row = blockIdx.x, tid = threadIdx.x;
  float* pr = r + (size_t)row * D_;
  __shared__ float s1[4], s2[4];
  float v[4];
#pragma unroll
  for (int i = 0; i < 4; ++i) v[i] = pr[i * 256 + tid];
  float s = v[0] + v[1] + v[2] + v[3];
#pragma unroll
  for (int o = 32; o > 0; o >>= 1) s += __shfl_down(s, o, 64);
  if ((tid & 63) == 0) s1[tid >> 6] = s;
  __syncthreads();
  float mu = (s1[0] + s1[1] + s1[2] + s1[3]) * (1.0f / D_);
  float d = 0.0f;
#pragma unroll
  for (int i = 0; i < 4; ++i) { float t = v[i] - mu; d += t * t; }
#pragma unroll
  for (int o = 32; o > 0; o >>= 1) d += __shfl_down(d, o, 64);
  if ((tid & 63) == 0) s2[tid >> 6] = d;
  __syncthreads();
  float var = (s2[0] + s2[1] + s2[2] + s2[3]) * (1.0f / D_);
  float inv = rsqrtf(var + 1e-5f);
#pragma unroll
  for (int i = 0; i < 4; ++i) {
    int c = i * 256 + tid;
    pr[c] = (v[i] - mu) * inv * g[c] + be[c];
  }
}

// ---------------------------------------------------------------- launch
extern "C" void kernel_launch(void* const* d_in, const int* in_sizes, int n_in,
                              void* d_out, int out_size, void* d_ws, size_t ws_size,
                              hipStream_t stream) {
  const float* x   = (const float*)d_in[0];
  // d_in[1] attn_mask: deterministic causal tril -> not read
  // d_in[2] ts: unused by reference
  const float* lam = (const float*)d_in[3];
  const float* qg  = (const float*)d_in[4];
  const float* kg  = (const float*)d_in[5];
  const float* vg  = (const float*)d_in[6];
  const float* tpb = (const float*)d_in[7];
  const float* pw  = (const float*)d_in[8];
  const float* pb  = (const float*)d_in[9];
  const float* ow  = (const float*)d_in[10];
  const float* ob  = (const float*)d_in[11];
  const float* hsc = (const float*)d_in[12];
  const float* lng = (const float*)d_in[13];
  const float* lnb = (const float*)d_in[14];
  float* out = (float*)d_out;

  char* ws = (char*)d_ws;
  // layout (bytes). aliasing: Qb<-xb, Kb<-pwb, Vtb<-hq, A2<-hk (all after last read)
  u16* xb   = (u16*)(ws + 0);          // 8 MB   x bf16
  u16* pwb  = (u16*)(ws + 8388608);    // 8 MB   proj_w bf16
  u16* owb  = (u16*)(ws + 16777216);   // 2 MB   out_w bf16
  u16* hu   = (u16*)(ws + 18874368);   // 8 MB
  u16* hv   = (u16*)(ws + 27262976);   // 8 MB
  u16* hq   = (u16*)(ws + 35651584);   // 8 MB
  u16* hk   = (u16*)(ws + 44040192);   // 8 MB
  float* pos = (float*)(ws + 52428800); // 16 KB
  u16* Qb  = xb;
  u16* Kb  = pwb;
  u16* Vtb = hq;
  u16* A2  = hk;

  k_conv_cum<<<9218, 256, 0, stream>>>(x, pw, ow, lam, xb, pwb, owb, pos);
  k_gemm1<<<dim3(32, 32), 256, 0, stream>>>(xb, pwb, pb, hu, hv, hq, hk);
  k_rope_vt<<<3072, 256, 0, stream>>>(hq, hk, hv, pos, qg, kg, vg, hsc, Qb, Kb, Vtb);
  k_attn<<<2048, 128, 0, stream>>>(Qb, Kb, Vtb, tpb, hu, A2);
  k_gemm2<<<dim3(8, 32), 256, 0, stream>>>(A2, owb, ob, x, out);
  k_ln<<<4096, 256, 0, stream>>>(out, lng, lnb);
}

// Round 7
// 291.794 us; speedup vs baseline: 1.3207x; 1.0164x over previous
//
#include <hip/hip_runtime.h>
#include <cstdint>
#include <cstddef>

typedef unsigned short u16;
typedef __attribute__((ext_vector_type(8))) short short8v;   // 8 x bf16 (4 VGPRs)
typedef __attribute__((ext_vector_type(4))) float f32x4;

#define B_   2
#define L_   2048
#define D_   1024
#define NH_  16
#define DH_  64
#define M_   (B_*L_)      /* 4096 */
#define N4_  (4*D_)       /* 4096 */

__device__ __forceinline__ float bf2f(u16 u) {
  union { float f; unsigned int i; } v; v.i = ((unsigned int)u) << 16; return v.f;
}
__device__ __forceinline__ u16 f2bf(float f) {
  union { float f; unsigned int i; } v; v.f = f;
  unsigned int x = v.i;
  return (u16)((x + 0x7fffu + ((x >> 16) & 1u)) >> 16);   // RNE
}
__device__ __forceinline__ unsigned int pk_bf16(float a, float b) {
#if __has_builtin(__builtin_amdgcn_cvt_pk_bf16_f32)
  auto r = __builtin_amdgcn_cvt_pk_bf16_f32(a, b);
  union { decltype(r) v; unsigned int u; } c; c.v = r; return c.u;
#else
  unsigned int r;
  asm("v_cvt_pk_bf16_f32 %0, %1, %2" : "=v"(r) : "v"(a), "v"(b));
  return r;
#endif
}
// silu via v_rcp_f32 (approx rcp, ~1ulp) instead of IEEE divide
__device__ __forceinline__ float siluf(float x) {
  return x * __builtin_amdgcn_rcpf(1.0f + __expf(-x));
}

// async global->LDS, 16B per lane. LDS dest = wave-uniform base + lane*16.
__device__ __forceinline__ void gl2lds16(const u16* g, u16* l) {
  __builtin_amdgcn_global_load_lds(
      (const __attribute__((address_space(1))) unsigned int*)(const void*)g,
      (__attribute__((address_space(3))) unsigned int*)(void*)l,
      16, 0, 0);
}

// ---------------------------------------------------------------- convert + cumsum (fused)
__global__ __launch_bounds__(256) void k_conv_cum(const float* __restrict__ x,
                                                  const float* __restrict__ pw,
                                                  const float* __restrict__ ow,
                                                  const float* __restrict__ lam,
                                                  u16* __restrict__ xb,
                                                  u16* __restrict__ pwb,
                                                  u16* __restrict__ owb,
                                                  float* __restrict__ pos) {
  const int NX = M_ * D_ / 4, NP = N4_ * D_ / 4;
  int bid = blockIdx.x;
  int tid = threadIdx.x;
  if (bid < 9216) {
    int i = bid * 256 + tid;
    const float* src; u16* dst; int j;
    if (i < NX)            { src = x;  dst = xb;  j = i; }
    else if (i < NX + NP)  { src = pw; dst = pwb; j = i - NX; }
    else                   { src = ow; dst = owb; j = i - NX - NP; }
    float4 v = ((const float4*)src)[j];
    ushort4 o; o.x = f2bf(v.x); o.y = f2bf(v.y); o.z = f2bf(v.z); o.w = f2bf(v.w);
    ((ushort4*)dst)[j] = o;
  } else {
    int b = bid - 9216;
    const float* in = lam + (size_t)b * L_;
    float* out = pos + (size_t)b * L_;
    float loc[8], s = 0.0f;
#pragma unroll
    for (int i = 0; i < 8; ++i) { loc[i] = in[tid * 8 + i]; s += loc[i]; }
    __shared__ float sb[256];
    sb[tid] = s;
    __syncthreads();
    for (int off = 1; off < 256; off <<= 1) {
      float t = (tid >= off) ? sb[tid - off] : 0.0f;
      __syncthreads();
      sb[tid] += t;
      __syncthreads();
    }
    float run = sb[tid] - s;   // exclusive prefix
#pragma unroll
    for (int i = 0; i < 8; ++i) { run += loc[i]; out[tid * 8 + i] = run; }
  }
}

// ---------------------------------------------------------------- GEMM1: h = silu(x @ pw^T + pb), split u/v/q/k
__global__ __launch_bounds__(256, 4) void k_gemm1(const u16* __restrict__ A,
                                                  const u16* __restrict__ Bw,
                                                  const float* __restrict__ bias,
                                                  u16* __restrict__ hu, u16* __restrict__ hv,
                                                  u16* __restrict__ hq, u16* __restrict__ hk) {
  const int K = D_;
  int bn = blockIdx.x, bm = blockIdx.y, tid = threadIdx.x;
  int w = tid >> 6, lane = tid & 63, quad = lane >> 4, r16 = lane & 15;
  __shared__ __align__(16) u16 As[8192], Bs[8192];   // 2 buffers x 128x32
  const u16* gA = A  + (size_t)(bm * 128) * K;
  const u16* gB = Bw + (size_t)(bn * 128) * K;
  int srow = tid >> 2, sc = tid & 3;
#pragma unroll
  for (int s = 0; s < 2; ++s) {
    int row = s * 64 + srow;
    int q = (sc - (row >> 1)) & 3;
    gl2lds16(gA + (size_t)row * K + q * 8, As + s * 2048 + w * 512);
    gl2lds16(gB + (size_t)row * K + q * 8, Bs + s * 2048 + w * 512);
  }
  f32x4 acc[4][4] = {};
  int wm = w & 1, wn = w >> 1;
  const int rowb = wm * 64, colb = wn * 64;
  for (int n = 0; n < 32; ++n) {
    __syncthreads();                       // drains stage(n)
    if (n + 1 < 32) {
      int kt = (n + 1) * 32, pb = (n + 1) & 1;
#pragma unroll
      for (int s = 0; s < 2; ++s) {
        int row = s * 64 + srow;
        int q = (sc - (row >> 1)) & 3;
        gl2lds16(gA + (size_t)row * K + kt + q * 8, As + pb * 4096 + s * 2048 + w * 512);
        gl2lds16(gB + (size_t)row * K + kt + q * 8, Bs + pb * 4096 + s * 2048 + w * 512);
      }
    }
    const u16* Ab = As + (n & 1) * 4096;
    const u16* Bb = Bs + (n & 1) * 4096;
    short8v af[4], bf[4];
#pragma unroll
    for (int mi = 0; mi < 4; ++mi) {
      int row = rowb + mi * 16 + r16;
      af[mi] = *(const short8v*)(Ab + (row * 4 + ((quad + (row >> 1)) & 3)) * 8);
    }
#pragma unroll
    for (int ni = 0; ni < 4; ++ni) {
      int row = colb + ni * 16 + r16;
      bf[ni] = *(const short8v*)(Bb + (row * 4 + ((quad + (row >> 1)) & 3)) * 8);
    }
#pragma unroll
    for (int mi = 0; mi < 4; ++mi)
#pragma unroll
      for (int ni = 0; ni < 4; ++ni)
        acc[mi][ni] = __builtin_amdgcn_mfma_f32_16x16x32_bf16(af[mi], bf[ni], acc[mi][ni], 0, 0, 0);
  }
  int nb = (bn * 128) >> 10;                 // which of u/v/q/k
  u16* dst = (nb == 0) ? hu : (nb == 1) ? hv : (nb == 2) ? hq : hk;
  int cbase = (bn * 128) & 1023;
  int row0 = bm * 128 + rowb;
#pragma unroll
  for (int ni = 0; ni < 4; ++ni) {
    int gcol = bn * 128 + colb + ni * 16 + r16;
    int lcol = cbase + colb + ni * 16 + r16;
    float bb = bias[gcol];
#pragma unroll
    for (int mi = 0; mi < 4; ++mi)
#pragma unroll
      for (int r = 0; r < 4; ++r) {
        int row = row0 + mi * 16 + quad * 4 + r;
        dst[(size_t)row * D_ + lcol] = f2bf(siluf(acc[mi][ni][r] + bb));
      }
  }
}

// ---------------------------------------------------------------- RoPE + gates (+head_scale into Q) and V gate+transpose (fused)
__global__ __launch_bounds__(256) void k_rope_vt(const u16* __restrict__ hq, const u16* __restrict__ hk,
                                                 const u16* __restrict__ hv,
                                                 const float* __restrict__ pos,
                                                 const float* __restrict__ qg, const float* __restrict__ kg,
                                                 const float* __restrict__ vg,
                                                 const float* __restrict__ hsc,
                                                 u16* __restrict__ Qb, u16* __restrict__ Kb,
                                                 u16* __restrict__ Vtb) {
  int bid = blockIdx.x;
  int tid = threadIdx.x;
  if (bid < 2048) {
    int idx = bid * 256 + tid;   // (bh*2048 + l)*8 + j4
    int j4 = idx & 7;
    int l  = (idx >> 3) & 2047;
    int bh = idx >> 14;
    int b = bh >> 4, hh = bh & 15;
    int row = b * L_ + l;
    float p = pos[row];
    float qs = qg[(size_t)row * NH_ + hh] * hsc[hh];
    float kgv = kg[(size_t)row * NH_ + hh];
    const u16* hqr = hq + (size_t)row * D_ + hh * DH_ + j4 * 8;
    const u16* hkr = hk + (size_t)row * D_ + hh * DH_ + j4 * 8;
    short8v qv = *(const short8v*)hqr;
    short8v kv = *(const short8v*)hkr;
    size_t ob = ((size_t)bh * L_ + l) * DH_ + j4 * 4;
    u16 qeo[4], qoo[4], keo[4], koo[4];
#pragma unroll
    for (int t = 0; t < 4; ++t) {
      int j = j4 * 4 + t;
      float inv = __expf(-(float)j * 0.28782313662425574f);  // 10000^(-2j/64)
      float a = p * inv;
      float c, s;
      __sincosf(a, &s, &c);
      float qe = bf2f((u16)qv[2 * t]), qo = bf2f((u16)qv[2 * t + 1]);
      float ke = bf2f((u16)kv[2 * t]), ko = bf2f((u16)kv[2 * t + 1]);
      qeo[t] = f2bf((qe * c - qo * s) * qs);
      qoo[t] = f2bf((qe * s + qo * c) * qs);
      keo[t] = f2bf((ke * c - ko * s) * kgv);
      koo[t] = f2bf((ke * s + ko * c) * kgv);
    }
    *(ushort4*)(Qb + ob)      = make_ushort4(qeo[0], qeo[1], qeo[2], qeo[3]);
    *(ushort4*)(Qb + ob + 32) = make_ushort4(qoo[0], qoo[1], qoo[2], qoo[3]);
    *(ushort4*)(Kb + ob)      = make_ushort4(keo[0], keo[1], keo[2], keo[3]);
    *(ushort4*)(Kb + ob + 32) = make_ushort4(koo[0], koo[1], koo[2], koo[3]);
  } else {
    int b2 = bid - 2048;
    int lt = b2 & 31;           // l-tile
    int bh = b2 >> 5;
    int b = bh >> 4, hh = bh & 15;
    __shared__ u16 t[64][68];   // pad to break transpose conflicts
    {
      int r = tid >> 2, cg = tid & 3;
      int row = b * L_ + lt * 64 + r;
      float gv = vg[(size_t)row * NH_ + hh];
      const u16* src = hv + (size_t)row * D_ + hh * DH_ + cg * 16;
      short8v v0 = ((const short8v*)src)[0];
      short8v v1 = ((const short8v*)src)[1];
#pragma unroll
      for (int e = 0; e < 8; ++e) {
        t[r][cg * 16 + e]     = f2bf(bf2f((u16)v0[e]) * gv);
        t[r][cg * 16 + 8 + e] = f2bf(bf2f((u16)v1[e]) * gv);
      }
    }
    __syncthreads();
    {
      int d = tid >> 2, lg = tid & 3;
      short8v o0, o1;
#pragma unroll
      for (int e = 0; e < 8; ++e) o0[e] = (short)t[lg * 16 + e][d];
#pragma unroll
      for (int e = 0; e < 8; ++e) o1[e] = (short)t[lg * 16 + 8 + e][d];
      u16* dst = Vtb + ((size_t)bh * DH_ + d) * L_ + lt * 64 + lg * 16;
      ((short8v*)dst)[0] = o0;
      ((short8v*)dst)[1] = o1;
    }
  }
}

// ---------------------------------------------------------------- fused causal gated attention + u-multiply
// v9 (proven round 5): 32-row tiles, 2 waves/block, KVBLK=64, LDS 16KB (Ks 8KB + Vs 8KB).
//     2048 blocks = 8 blocks/CU x 2 waves = 16 waves/CU structural; barriers sync only 2 waves;
//     triangular imbalance at 64-tier granularity, longest-first, same-bh -> same-XCD.
//       b1: K(jt) drained, Vs free -> stage V(jt); QK from Ks
//       b2: V(jt) drained, Ks free -> stage K(jt+1), prefetch bias(jt+1); PV from Vs
__global__ __launch_bounds__(128, 4) void k_attn(const u16* __restrict__ Qb, const u16* __restrict__ Kb,
                                                 const u16* __restrict__ Vtb, const float* __restrict__ tpb,
                                                 const u16* __restrict__ hu, u16* __restrict__ A2) {
  int id = blockIdx.x;
  int bh = (id & 7) + 8 * ((id >> 3) & 3);   // same-bh blocks land on same XCD (id%8 round-robin)
  int t  = 63 - (id >> 5);                   // 32-row i-tile, longest (t=63) first
  int b = bh >> 4, hh = bh & 15;
  int tid = threadIdx.x, w = tid >> 6, lane = tid & 63, quad = lane >> 4, r16 = lane & 15;
  __shared__ __align__(16) u16 Ks[4096];   // 2 d-halves x (64 j x 32 d), content-rotated
  __shared__ __align__(16) u16 Vs[4096];   // 2 j-slices x (64 d x 32 j), content-rotated
  const size_t bhbase = (size_t)bh * L_ * DH_;
  const int irow = t * 32 + w * 16;        // wave's 16 i-rows
  const int gimax_w = irow + 15;
  const int jmax = t >> 1;                 // 64-j iterations cover j <= t*32+31
  // Q fragment (B-operand: n=i, k=d)
  const u16* qt = Qb + bhbase + (size_t)irow * DH_;
  short8v bq[2];
#pragma unroll
  for (int ks = 0; ks < 2; ++ks)
    bq[ks] = *(const short8v*)(qt + (size_t)r16 * DH_ + ks * 32 + quad * 8);
  int srow = tid >> 2, sc = tid & 3;       // staging: srow 0..31, quad-slot 0..3
  // stage K(0)
#pragma unroll
  for (int s = 0; s < 4; ++s) {
    int half = s & 1, h = s >> 1;
    int row = half * 32 + srow;            // j-row 0..63
    int q = (sc - (row >> 1)) & 3;
    gl2lds16(Kb + bhbase + (size_t)row * DH_ + h * 32 + q * 8,
             Ks + h * 2048 + half * 1024 + w * 512);
  }
  // bias row pointer (lane's own i-row); prefetch bias(0)
  const float* bbase = tpb + ((size_t)(b * L_ + irow + r16)) * L_ + quad * 4;
  float4 bv[4];
#pragma unroll
  for (int tj = 0; tj < 4; ++tj)
    if (tj * 16 <= gimax_w) bv[tj] = *(const float4*)(bbase + tj * 16);
  f32x4 accy[4] = {};
  for (int jt = 0; jt <= jmax; ++jt) {
    __syncthreads();   // b1: K(jt)+bias(jt) drained; Vs free (prev PV done)
    // stage V(jt)
#pragma unroll
    for (int s = 0; s < 4; ++s) {
      int half = s & 1, sl = s >> 1;
      int row = half * 32 + srow;          // d-row 0..63
      int q = (sc - (row >> 1)) & 3;
      gl2lds16(Vtb + bhbase + (size_t)row * L_ + jt * 64 + sl * 32 + q * 8,
               Vs + sl * 2048 + half * 1024 + w * 512);
    }
    // ---- QK over 4 16-j subtiles (S^T = K.Q^T); bias+silu+mask+pack
    unsigned int W[4][2];
#pragma unroll
    for (int tj = 0; tj < 4; ++tj) {
      int jlo = jt * 64 + tj * 16;
      unsigned int p01 = 0, p23 = 0;
      if (jlo <= gimax_w) {                // subtile touched (wave-uniform)
        int jr = tj * 16 + r16;
        int sw = (quad + (jr >> 1)) & 3;
        short8v ak0 = *(const short8v*)(Ks + jr * 32 + sw * 8);
        short8v ak1 = *(const short8v*)(Ks + 2048 + jr * 32 + sw * 8);
        f32x4 acc = {};
        acc = __builtin_amdgcn_mfma_f32_16x16x32_bf16(ak0, bq[0], acc, 0, 0, 0);
        acc = __builtin_amdgcn_mfma_f32_16x16x32_bf16(ak1, bq[1], acc, 0, 0, 0);
        float4 bvx = bv[tj];
        if (jlo + 15 <= irow) {            // fully unmasked subtile (majority)
          p01 = pk_bf16(siluf(fmaf(4.0f, bvx.x, acc[0])), siluf(fmaf(4.0f, bvx.y, acc[1])));
          p23 = pk_bf16(siluf(fmaf(4.0f, bvx.z, acc[2])), siluf(fmaf(4.0f, bvx.w, acc[3])));
        } else {                           // diagonal subtile: per-element mask
          int gi = irow + r16;
          int j0 = jlo + quad * 4;
          float v0 = (j0     <= gi) ? siluf(fmaf(4.0f, bvx.x, acc[0])) : 0.0f;
          float v1 = (j0 + 1 <= gi) ? siluf(fmaf(4.0f, bvx.y, acc[1])) : 0.0f;
          float v2 = (j0 + 2 <= gi) ? siluf(fmaf(4.0f, bvx.z, acc[2])) : 0.0f;
          float v3 = (j0 + 3 <= gi) ? siluf(fmaf(4.0f, bvx.w, acc[3])) : 0.0f;
          p01 = pk_bf16(v0, v1);
          p23 = pk_bf16(v2, v3);
        }
      }
      W[tj][0] = p01; W[tj][1] = p23;
    }
    __syncthreads();   // b2: V(jt) drained; all waves done reading Ks(jt)
    // stage K(jt+1) and prefetch bias(jt+1) (drain at next b1, covered by PV)
    if (jt < jmax) {
      const size_t kb = bhbase + (size_t)(jt + 1) * 64 * DH_;
#pragma unroll
      for (int s = 0; s < 4; ++s) {
        int half = s & 1, h = s >> 1;
        int row = half * 32 + srow;
        int q = (sc - (row >> 1)) & 3;
        gl2lds16(Kb + kb + (size_t)row * DH_ + h * 32 + q * 8,
                 Ks + h * 2048 + half * 1024 + w * 512);
      }
      int jn = (jt + 1) * 64;
#pragma unroll
      for (int tj = 0; tj < 4; ++tj)
        if (jn + tj * 16 <= gimax_w) bv[tj] = *(const float4*)(bbase + jn + tj * 16);
    }
    // ---- redistribute subtile pairs to PV A-fragments: paw[k2]
    unsigned int paw[2][4];
#pragma unroll
    for (int k2 = 0; k2 < 2; ++k2)
#pragma unroll
      for (int p = 0; p < 2; ++p) {
        unsigned int x = W[2 * k2][p], y = W[2 * k2 + 1][p];
        asm("v_permlane32_swap_b32 %0, %1" : "+v"(x), "+v"(y));
        asm("v_permlane16_swap_b32 %0, %1" : "+v"(x), "+v"(y));
        paw[k2][p]     = x;
        paw[k2][2 + p] = y;
      }
    // ---- PV: register P x Vs
#pragma unroll
    for (int k2 = 0; k2 < 2; ++k2) {
      if (jt * 64 + k2 * 32 > gimax_w) continue;   // wave-uniform slice skip
      union { unsigned int u[4]; short8v s8; } pu;
      pu.u[0] = paw[k2][0]; pu.u[1] = paw[k2][1]; pu.u[2] = paw[k2][2]; pu.u[3] = paw[k2][3];
#pragma unroll
      for (int ni = 0; ni < 4; ++ni) {
        int vr = ni * 16 + r16;
        int sw = (quad + (vr >> 1)) & 3;
        short8v vb = *(const short8v*)(Vs + k2 * 2048 + vr * 32 + sw * 8);
        accy[ni] = __builtin_amdgcn_mfma_f32_16x16x32_bf16(pu.s8, vb, accy[ni], 0, 0, 0);
      }
    }
  }
  // final epilogue: y * u -> A2 (b, l, h*64+d) bf16
  const u16* hup = hu + ((size_t)(b * L_ + irow)) * D_ + hh * DH_;
  u16* a2p = A2 + ((size_t)(b * L_ + irow)) * D_ + hh * DH_;
#pragma unroll
  for (int ni = 0; ni < 4; ++ni) {
    int d = ni * 16 + r16;
#pragma unroll
    for (int rreg = 0; rreg < 4; ++rreg) {
      int lr = quad * 4 + rreg;
      float u = bf2f(hup[(size_t)lr * D_ + d]);
      a2p[(size_t)lr * D_ + d] = f2bf(accy[ni][rreg] * u);
    }
  }
}

// ---------------------------------------------------------------- GEMM2: r = (y*u) @ ow^T + ob + x
// v2: 128x64 tiles, grid (16,32) = 512 blocks = 2 blocks/CU (was 1) so blocks overlap.
__global__ __launch_bounds__(256, 4) void k_gemm2(const u16* __restrict__ A,
                                                  const u16* __restrict__ Bw,
                                                  const float* __restrict__ bias,
                                                  const float* __restrict__ xres,
                                                  float* __restrict__ out) {
  const int K = D_;
  int bn = blockIdx.x, bm = blockIdx.y, tid = threadIdx.x;
  int w = tid >> 6, lane = tid & 63, quad = lane >> 4, r16 = lane & 15;
  __shared__ __align__(16) u16 As[8192];   // 2 bufs x 128x32
  __shared__ __align__(16) u16 Bs[4096];   // 2 bufs x 64x32
  const u16* gA = A  + (size_t)(bm * 128) * K;
  const u16* gB = Bw + (size_t)(bn * 64) * K;
  int srow = tid >> 2, sc = tid & 3;
  // prologue stage(0)
#pragma unroll
  for (int s = 0; s < 2; ++s) {
    int row = s * 64 + srow;
    int q = (sc - (row >> 1)) & 3;
    gl2lds16(gA + (size_t)row * K + q * 8, As + s * 2048 + w * 512);
  }
  {
    int q = (sc - (srow >> 1)) & 3;
    gl2lds16(gB + (size_t)srow * K + q * 8, Bs + w * 512);
  }
  f32x4 acc[4][2] = {};
  int wm = w & 1, wn = w >> 1;
  const int rowb = wm * 64, colb = wn * 32;
  for (int n = 0; n < 32; ++n) {
    __syncthreads();
    if (n + 1 < 32) {
      int kt = (n + 1) * 32, pb = (n + 1) & 1;
#pragma unroll
      for (int s = 0; s < 2; ++s) {
        int row = s * 64 + srow;
        int q = (sc - (row >> 1)) & 3;
        gl2lds16(gA + (size_t)row * K + kt + q * 8, As + pb * 4096 + s * 2048 + w * 512);
      }
      int q = (sc - (srow >> 1)) & 3;
      gl2lds16(gB + (size_t)srow * K + kt + q * 8, Bs + pb * 2048 + w * 512);
    }
    const u16* Ab = As + (n & 1) * 4096;
    const u16* Bb = Bs + (n & 1) * 2048;
    short8v af[4], bf[2];
#pragma unroll
    for (int mi = 0; mi < 4; ++mi) {
      int row = rowb + mi * 16 + r16;
      af[mi] = *(const short8v*)(Ab + (row * 4 + ((quad + (row >> 1)) & 3)) * 8);
    }
#pragma unroll
    for (int ni = 0; ni < 2; ++ni) {
      int row = colb + ni * 16 + r16;
      bf[ni] = *(const short8v*)(Bb + (row * 4 + ((quad + (row >> 1)) & 3)) * 8);
    }
#pragma unroll
    for (int mi = 0; mi < 4; ++mi)
#pragma unroll
      for (int ni = 0; ni < 2; ++ni)
        acc[mi][ni] = __builtin_amdgcn_mfma_f32_16x16x32_bf16(af[mi], bf[ni], acc[mi][ni], 0, 0, 0);
  }
  int row0 = bm * 128 + rowb, col0 = bn * 64 + colb;
#pragma unroll
  for (int ni = 0; ni < 2; ++ni) {
    int col = col0 + ni * 16 + r16;
    float bb = bias[col];
#pragma unroll
    for (int mi = 0; mi < 4; ++mi)
#pragma unroll
      for (int r = 0; r < 4; ++r) {
        int row = row0 + mi * 16 + quad * 4 + r;
        out[(size_t)row * D_ + col] = acc[mi][ni][r] + bb + xres[(size_t)row * D_ + col];
      }
  }
}

// ---------------------------------------------------------------- LayerNorm (in place on d_out)
__global__ __launch_bounds__(256) void k_ln(float* __restrict__ r,
                                            const float* __restrict__ g,
                                            const float* __restrict__ be) {
  int row = blockIdx.x, tid = threadIdx.x;
  float* pr = r + (size_t)row * D_;
  __shared__ float s1[4], s2[4];
  float v[4];
#pragma unroll
  for (int i = 0; i < 4; ++i) v[i] = pr[i * 256 + tid];
  float s = v[0] + v[1] + v[2] + v[3];
#pragma unroll
  for (int o = 32; o > 0; o >>= 1) s += __shfl_down(s, o, 64);
  if ((tid & 63) == 0) s1[tid >> 6] = s;
  __syncthreads();
  float mu = (s1[0] + s1[1] + s1[2] + s1[3]) * (1.0f / D_);
  float d = 0.0f;
#pragma unroll
  for (int i = 0; i < 4; ++i) { float t = v[i] - mu; d += t * t; }
#pragma unroll
  for (int o = 32; o > 0; o >>= 1) d += __shfl_down(d, o, 64);
  if ((tid & 63) == 0) s2[tid >> 6] = d;
  __syncthreads();
  float var = (s2[0] + s2[1] + s2[2] + s2[3]) * (1.0f / D_);
  float inv = rsqrtf(var + 1e-5f);
#pragma unroll
  for (int i = 0; i < 4; ++i) {
    int c = i * 256 + tid;
    pr[c] = (v[i] - mu) * inv * g[c] + be[c];
  }
}

// ---------------------------------------------------------------- launch
extern "C" void kernel_launch(void* const* d_in, const int* in_sizes, int n_in,
                              void* d_out, int out_size, void* d_ws, size_t ws_size,
                              hipStream_t stream) {
  const float* x   = (const float*)d_in[0];
  // d_in[1] attn_mask: deterministic causal tril -> not read
  // d_in[2] ts: unused by reference
  const float* lam = (const float*)d_in[3];
  const float* qg  = (const float*)d_in[4];
  const float* kg  = (const float*)d_in[5];
  const float* vg  = (const float*)d_in[6];
  const float* tpb = (const float*)d_in[7];
  const float* pw  = (const float*)d_in[8];
  const float* pb  = (const float*)d_in[9];
  const float* ow  = (const float*)d_in[10];
  const float* ob  = (const float*)d_in[11];
  const float* hsc = (const float*)d_in[12];
  const float* lng = (const float*)d_in[13];
  const float* lnb = (const float*)d_in[14];
  float* out = (float*)d_out;

  char* ws = (char*)d_ws;
  // layout (bytes). aliasing: Qb<-xb, Kb<-pwb, Vtb<-hq, A2<-hk (all after last read)
  u16* xb   = (u16*)(ws + 0);          // 8 MB   x bf16
  u16* pwb  = (u16*)(ws + 8388608);    // 8 MB   proj_w bf16
  u16* owb  = (u16*)(ws + 16777216);   // 2 MB   out_w bf16
  u16* hu   = (u16*)(ws + 18874368);   // 8 MB
  u16* hv   = (u16*)(ws + 27262976);   // 8 MB
  u16* hq   = (u16*)(ws + 35651584);   // 8 MB
  u16* hk   = (u16*)(ws + 44040192);   // 8 MB
  float* pos = (float*)(ws + 52428800); // 16 KB
  u16* Qb  = xb;
  u16* Kb  = pwb;
  u16* Vtb = hq;
  u16* A2  = hk;

  k_conv_cum<<<9218, 256, 0, stream>>>(x, pw, ow, lam, xb, pwb, owb, pos);
  k_gemm1<<<dim3(32, 32), 256, 0, stream>>>(xb, pwb, pb, hu, hv, hq, hk);
  k_rope_vt<<<3072, 256, 0, stream>>>(hq, hk, hv, pos, qg, kg, vg, hsc, Qb, Kb, Vtb);
  k_attn<<<2048, 128, 0, stream>>>(Qb, Kb, Vtb, tpb, hu, A2);
  k_gemm2<<<dim3(16, 32), 256, 0, stream>>>(A2, owb, ob, x, out);
  k_ln<<<4096, 256, 0, stream>>>(out, lng, lnb);
}